// Round 2
// 177.786 us; speedup vs baseline: 1.0178x; 1.0178x over previous
//
#include <hip/hip_runtime.h>
#include <math.h>

typedef _Float16 half_t;
typedef _Float16 half8 __attribute__((ext_vector_type(8)));
typedef _Float16 half4v __attribute__((ext_vector_type(4)));
typedef float float4v __attribute__((ext_vector_type(4)));
typedef float float16v __attribute__((ext_vector_type(16)));

#define AS1 __attribute__((address_space(1)))
#define AS3 __attribute__((address_space(3)))

#define MFMA16(a, b, c) __builtin_amdgcn_mfma_f32_16x16x32_f16((a), (b), (c), 0, 0, 0)
#define MFMA32(a, b, c) __builtin_amdgcn_mfma_f32_32x32x16_f16((a), (b), (c), 0, 0, 0)

// exp2-domain softmax: q is pre-scaled by 0.125*log2(e) in qkv_gemm.
#define QSCALE 0.18033688f          // 0.125 * 1.44269504
#define TABOFF 2.88539008f          // 2.0 * 1.44269504

__device__ __forceinline__ void gload16(const half_t* g, half_t* l) {
    __builtin_amdgcn_global_load_lds((const AS1 void*)g, (AS3 void*)l, 16, 0, 0);
}

__device__ __forceinline__ int iclamp(int v, int lo, int hi) {
    return v < lo ? lo : (v > hi ? hi : v);
}

// =====================================================================
// cast: fp32 -> fp16 for q, W_in, W_out, rel_pe (padded to 160 rows)
// =====================================================================
__global__ __launch_bounds__(256) void cast_kernel(
    const float* __restrict__ q, const float* __restrict__ w_in,
    const float* __restrict__ w_out, const float* __restrict__ pe,
    half_t* __restrict__ q16, half_t* __restrict__ w16,
    half_t* __restrict__ wo16, half_t* __restrict__ pe16)
{
    const int tid = blockIdx.x * 256 + threadIdx.x;
    const int stride = gridDim.x * 256;
    for (int i = tid; i < 1048576; i += stride) {
        float4 v = ((const float4*)q)[i];
        *(half4v*)(q16 + (size_t)i * 4) =
            (half4v){(half_t)v.x, (half_t)v.y, (half_t)v.z, (half_t)v.w};
    }
    for (int i = tid; i < 786432; i += stride) {
        float4 v = ((const float4*)w_in)[i];
        *(half4v*)(w16 + (size_t)i * 4) =
            (half4v){(half_t)v.x, (half_t)v.y, (half_t)v.z, (half_t)v.w};
    }
    for (int i = tid; i < 262144; i += stride) {
        float4 v = ((const float4*)w_out)[i];
        *(half4v*)(wo16 + (size_t)i * 4) =
            (half4v){(half_t)v.x, (half_t)v.y, (half_t)v.z, (half_t)v.w};
    }
    for (int i = tid; i < 2064; i += stride) {
        float4 v = ((const float4*)pe)[i];
        *(half4v*)(pe16 + (size_t)i * 4) =
            (half4v){(half_t)v.x, (half_t)v.y, (half_t)v.z, (half_t)v.w};
    }
    for (int i = tid; i < 496; i += stride) {   // pad rows 129..159 = 0
        *(half4v*)(pe16 + 8256 + (size_t)i * 4) = (half4v){0, 0, 0, 0};
    }
}

// =====================================================================
// fp16 MFMA NT GEMM, 128x128 tile, BK=32, 256 thr (4 waves in 2x2).
// 1-D grid, XCD-aware rectangle mapping. (R4 version — measured good.)
// =====================================================================
__global__ __launch_bounds__(256) void qkv_gemm(
    const half_t* __restrict__ A, const half_t* __restrict__ W,
    const float* __restrict__ bias,
    half_t* __restrict__ qh, half_t* __restrict__ kh, half_t* __restrict__ vt)
{
    __shared__ half_t As[128 * 32];
    __shared__ half_t Bs[128 * 32];
    const int K = 1024;
    const int tid = threadIdx.x, lane = tid & 63, wid = tid >> 6;
    const int wm = wid & 1, wn = wid >> 1;
    const int bid = blockIdx.x;
    const int xcd = bid & 7, idx = bid >> 3;
    const int m0 = (((xcd >> 1) << 3) + (idx & 7)) * 128;
    const int n0 = (((xcd & 1) * 12) + (idx >> 3)) * 128;

    const half_t* gA[2]; const half_t* gB[2];
    half_t* lA[2]; half_t* lB[2];
    {
        const int base = wid * 128;
#pragma unroll
        for (int c = 0; c < 2; ++c) {
            int slot = base + c * 64 + lane;
            int row = slot >> 2;
            int ch = (slot & 3) ^ ((row >> 1) & 3);
            gA[c] = A + (size_t)(m0 + row) * K + ch * 8;
            gB[c] = W + (size_t)(n0 + row) * K + ch * 8;
            lA[c] = As + (base + c * 64) * 8;
            lB[c] = Bs + (base + c * 64) * 8;
        }
    }
    int aOff[4], bOff[4];
#pragma unroll
    for (int i = 0; i < 4; ++i) {
        int ra = wm * 64 + i * 16 + (lane & 15);
        aOff[i] = ra * 32 + (((lane >> 4) ^ ((ra >> 1) & 3)) * 8);
        int rb = wn * 64 + i * 16 + (lane & 15);
        bOff[i] = rb * 32 + (((lane >> 4) ^ ((rb >> 1) & 3)) * 8);
    }
    float4v acc[4][4];
#pragma unroll
    for (int i = 0; i < 4; ++i)
#pragma unroll
        for (int j = 0; j < 4; ++j) acc[i][j] = (float4v){0.f, 0.f, 0.f, 0.f};

    for (int k0 = 0; k0 < K; k0 += 32) {
        __syncthreads();
        gload16(gA[0], lA[0]); gload16(gA[1], lA[1]);
        gload16(gB[0], lB[0]); gload16(gB[1], lB[1]);
        gA[0] += 32; gA[1] += 32; gB[0] += 32; gB[1] += 32;
        __syncthreads();
        half8 af[4], bf[4];
#pragma unroll
        for (int i = 0; i < 4; ++i) af[i] = *(const half8*)(As + aOff[i]);
#pragma unroll
        for (int j = 0; j < 4; ++j) bf[j] = *(const half8*)(Bs + bOff[j]);
#pragma unroll
        for (int i = 0; i < 4; ++i)
#pragma unroll
            for (int j = 0; j < 4; ++j)
                acc[i][j] = MFMA16(af[i], bf[j], acc[i][j]);
    }

    const int part = n0 >> 10;
#pragma unroll
    for (int ni = 0; ni < 4; ++ni) {
        const int col = n0 + wn * 64 + ni * 16 + (lane & 15);
        const float bv = bias[col];
        const int hh = (col >> 6) & 15, d = col & 63;
#pragma unroll
        for (int mi = 0; mi < 4; ++mi) {
            const int r0 = m0 + wm * 64 + mi * 16 + ((lane >> 4) << 2);
            const int bb = r0 >> 10, l0 = r0 & 1023;
            if (part == 0) {
#pragma unroll
                for (int r = 0; r < 4; ++r)
                    qh[(((size_t)(bb * 16 + hh) * 1024) + l0 + r) * 64 + d] =
                        (half_t)((acc[mi][ni][r] + bv) * QSCALE);
            } else if (part == 1) {
#pragma unroll
                for (int r = 0; r < 4; ++r)
                    kh[(((size_t)(bb * 16 + hh) * 1024) + l0 + r) * 64 + d] =
                        (half_t)(acc[mi][ni][r] + bv);
            } else {
                half4v pk;
#pragma unroll
                for (int r = 0; r < 4; ++r) pk[r] = (half_t)(acc[mi][ni][r] + bv);
                *(half4v*)(vt + ((size_t)(bb * 16 + hh) * 64 + d) * 1024 + l0) = pk;
            }
        }
    }
}

// =====================================================================
// out GEMM: 128x64 tiles -> 512 blocks (2/CU). (R9 version — banked win.)
// =====================================================================
__global__ __launch_bounds__(256) void out_gemm(
    const half_t* __restrict__ A, const half_t* __restrict__ W,
    const float* __restrict__ bias, float* __restrict__ C)
{
    __shared__ half_t As[128 * 32];
    __shared__ half_t Bs[64 * 32];
    const int K = 1024;
    const int tid = threadIdx.x, lane = tid & 63, wid = tid >> 6;
    const int wm = wid & 1, wn = wid >> 1;
    const int bid = blockIdx.x;
    const int xcd = bid & 7, idx = bid >> 3;
    const int m0 = ((xcd << 2) + (idx >> 4)) * 128;
    const int n0 = (idx & 15) * 64;

    const half_t* gA[2]; const half_t* gB1;
    half_t* lA[2]; half_t* lB1;
    {
        const int base = wid * 128;
#pragma unroll
        for (int c = 0; c < 2; ++c) {
            int slot = base + c * 64 + lane;
            int row = slot >> 2;
            int ch = (slot & 3) ^ ((row >> 1) & 3);
            gA[c] = A + (size_t)(m0 + row) * K + ch * 8;
            lA[c] = As + (base + c * 64) * 8;
        }
        int slotB = wid * 64 + lane;
        int rowB = slotB >> 2;
        int chB = (slotB & 3) ^ ((rowB >> 1) & 3);
        gB1 = W + (size_t)(n0 + rowB) * K + chB * 8;
        lB1 = Bs + (wid * 64) * 8;
    }
    int aOff[4], bOff[2];
#pragma unroll
    for (int i = 0; i < 4; ++i) {
        int ra = wm * 64 + i * 16 + (lane & 15);
        aOff[i] = ra * 32 + (((lane >> 4) ^ ((ra >> 1) & 3)) * 8);
    }
#pragma unroll
    for (int j = 0; j < 2; ++j) {
        int rb = wn * 32 + j * 16 + (lane & 15);
        bOff[j] = rb * 32 + (((lane >> 4) ^ ((rb >> 1) & 3)) * 8);
    }
    float4v acc[4][2];
#pragma unroll
    for (int i = 0; i < 4; ++i)
#pragma unroll
        for (int j = 0; j < 2; ++j) acc[i][j] = (float4v){0.f, 0.f, 0.f, 0.f};

    for (int k0 = 0; k0 < K; k0 += 32) {
        __syncthreads();
        gload16(gA[0], lA[0]); gload16(gA[1], lA[1]);
        gload16(gB1, lB1);
        gA[0] += 32; gA[1] += 32; gB1 += 32;
        __syncthreads();
        half8 af[4], bf[2];
#pragma unroll
        for (int i = 0; i < 4; ++i) af[i] = *(const half8*)(As + aOff[i]);
#pragma unroll
        for (int j = 0; j < 2; ++j) bf[j] = *(const half8*)(Bs + bOff[j]);
#pragma unroll
        for (int i = 0; i < 4; ++i)
#pragma unroll
            for (int j = 0; j < 2; ++j)
                acc[i][j] = MFMA16(af[i], bf[j], acc[i][j]);
    }

#pragma unroll
    for (int ni = 0; ni < 2; ++ni) {
        const int col = n0 + wn * 32 + ni * 16 + (lane & 15);
        const float bv = bias[col];
#pragma unroll
        for (int mi = 0; mi < 4; ++mi) {
            const int r0 = m0 + wm * 64 + mi * 16 + ((lane >> 4) << 2);
#pragma unroll
            for (int r = 0; r < 4; ++r)
                C[(size_t)(r0 + r) * 1024 + col] = acc[mi][ni][r] + bv;
        }
    }
}

// =====================================================================
// MFMA flash attention v5 (R1 fix: permlane operand/output order):
//  - KV double-buffered (2x8192 halves) with counted s_waitcnt vmcnt(4)
//    + raw s_barrier (no vmcnt(0) drain in the loop): tile kt+1's DMA
//    overlaps tile kt's compute (T3/T4-lite).
//  - Pm LDS round-trip replaced by v_permlane32_swap register exchange
//    (T12): swap(A,B) -> r[0]=[A.row0|B.row0] (word j<2),
//    r[1]=[A.row1|B.row1] (word j>=2). LDS 76800 B -> 2 blocks/CU.
//  - exp2-domain softmax (log2e folded into q scale) -> bare v_exp_f32.
// C/D layout: col=lane&31, row=(reg&3)+8*(reg>>2)+4*(lane>>5).
// A/B layout: row|col=lane&31, k=(lane>>5)*8+j per 16-k chunk.
// =====================================================================
__global__ __launch_bounds__(256) void attn_mfma(
    const half_t* __restrict__ qh, const half_t* __restrict__ kh,
    const half_t* __restrict__ vt, const half_t* __restrict__ pe,
    half_t* __restrict__ ao)
{
    __shared__ half_t KV[2 * 8192];        // dbuf [K 64x64 | V^T 64x64] swizzled
    __shared__ half_t R2[4 * 32 * 172];    // per-wave skewed bias, stride 172

    const int tid = threadIdx.x, lane = tid & 63, wid = tid >> 6;
    const int hl = lane >> 5, ql = lane & 31;
    const int bid = blockIdx.x;
    const int xcd = bid & 7, idx = bid >> 3;
    const int bh = xcd + ((idx >> 3) << 3);
    const int q0 = (idx & 7) * 128;
    const int h = bh & 15, b = bh >> 4;
    const int i0w = q0 + wid * 32;
    const size_t hbase = (size_t)(b * 16 + h) * 64 * 1024;
    const half_t* Qg = qh + hbase;
    const half_t* Kg = kh + hbase;
    const half_t* Vg = vt + hbase;

    // ---- staging pointers (slots 0..511 K, 512..1023 V^T) ----
    const half_t* gS[4]; int lOff[4]; int ginc[4];
#pragma unroll
    for (int c = 0; c < 4; ++c) {
        const int slot0 = wid * 256 + c * 64;
        const int slot = slot0 + lane;
        if (slot0 < 512) {
            int srow = slot >> 3, sch = (slot & 7) ^ (srow & 7);
            gS[c] = Kg + srow * 64 + sch * 8;
            ginc[c] = 64 * 64;
            lOff[c] = slot0 * 8;
        } else {
            int s2 = slot - 512;
            int srow = s2 >> 3, sch = (s2 & 7) ^ (srow & 7);
            gS[c] = Vg + srow * 1024 + sch * 8;
            ginc[c] = 64;
            lOff[c] = 4096 + (slot0 - 512) * 8;
        }
    }

    // stage tile 0 into buffer 0 (DMA overlaps the R2 table build below)
#pragma unroll
    for (int c = 0; c < 4; ++c) { gload16(gS[c], KV + lOff[c]); gS[c] += ginc[c]; }

    // Q fragment: element [q=ql][d = cc*16 + hl*8 + j]
    const int qrow = i0w + ql;
    half8 qb[4];
#pragma unroll
    for (int cc = 0; cc < 4; ++cc)
        qb[cc] = *(const half8*)(Qg + (size_t)qrow * 64 + cc * 16 + hl * 8);

    // ---- build skewed bias table (wave-private): entry[il][ts] ----
    // interior ts = col+4+il (col = rel+64); plateaus: [0, il+4] = col0,
    // [il+132, il+139] = col128. Read clamp hi = 128+((ql+3)&~3).
    half_t* r2w = R2 + wid * (32 * 172);
#pragma unroll
    for (int j2 = 0; j2 < 5; ++j2) {
        float16v c;
#pragma unroll
        for (int r = 0; r < 16; ++r) c[r] = 0.f;
#pragma unroll
        for (int cc = 0; cc < 4; ++cc) {
            half8 pb = *(const half8*)(pe + (size_t)(j2 * 32 + ql) * 64 + cc * 16 + hl * 8);
            c = MFMA32(qb[cc], pb, c);
        }
        const int col = j2 * 32 + ql;
        if (col < 129) {
#pragma unroll
            for (int reg = 0; reg < 16; ++reg) {
                const int il = (reg & 3) + 8 * (reg >> 2) + 4 * hl;
                const half_t hv = (half_t)(c[reg] - TABOFF);
                if (col == 0) {
                    for (int ts = 0; ts <= il + 4; ++ts) r2w[il * 172 + ts] = hv;
                } else if (col == 128) {
                    for (int ts = il + 132; ts <= il + 139; ++ts) r2w[il * 172 + ts] = hv;
                } else {
                    r2w[il * 172 + col + 4 + il] = hv;
                }
            }
        }
    }
    // table committed before k-loop reads (wave-private LDS)
    asm volatile("s_waitcnt lgkmcnt(0)" ::: "memory");

    // ---- frag LDS offsets (within one 8192-half buffer) ----
    int kOff[2][4], vOff[2][4];
#pragma unroll
    for (int t2 = 0; t2 < 2; ++t2)
#pragma unroll
        for (int cc = 0; cc < 4; ++cc) {
            int row = t2 * 32 + ql;
            int ch = (cc * 2 + hl) ^ (row & 7);
            kOff[t2][cc] = row * 64 + ch * 8;
            vOff[t2][cc] = 4096 + row * 64 + ch * 8;
        }

    const int hiC = 128 + ((ql + 3) & ~3);   // per-thread bias clamp (mult of 4)
    const half_t* r2row = r2w + ql * 172;

    float l_r = 0.f;
    float16v oacc[2];
#pragma unroll
    for (int dt = 0; dt < 2; ++dt)
#pragma unroll
        for (int r = 0; r < 16; ++r) oacc[dt][r] = 0.f;

    for (int kt2 = 0; kt2 < 8; ++kt2) {
#pragma unroll
        for (int kk = 0; kk < 2; ++kk) {
            const int kt = kt2 * 2 + kk;
            // prefetch tile kt+1 into the other buffer; keep it in flight
            if (kt < 15) {
#pragma unroll
                for (int c = 0; c < 4; ++c) {
                    gload16(gS[c], KV + (kk ^ 1) * 8192 + lOff[c]);
                    gS[c] += ginc[c];
                }
                asm volatile("s_waitcnt vmcnt(4)" ::: "memory"); // own tile-kt loads done
            } else {
                asm volatile("s_waitcnt vmcnt(0)" ::: "memory");
            }
            __builtin_amdgcn_s_barrier();          // all waves' tile-kt DMA landed
            asm volatile("" ::: "memory");

            const half_t* KVb = KV + kk * 8192;

            // S^T = K.Q^T with bias C-init; p = exp2(s) kept in registers
            half4v preg[2][4];
#pragma unroll
            for (int t2 = 0; t2 < 2; ++t2) {
                float16v s;
#pragma unroll
                for (int g = 0; g < 4; ++g) {
                    int traw = kt * 64 + t2 * 32 + 8 * g + 4 * hl + 64 - i0w;
                    int tsb = iclamp(traw, -4, hiC) + 4;
                    half4v bh4 = *(const half4v*)(r2row + tsb);
#pragma unroll
                    for (int r = 0; r < 4; ++r) s[4 * g + r] = (float)bh4[r];
                }
#pragma unroll
                for (int cc = 0; cc < 4; ++cc) {
                    half8 kf = *(const half8*)(KVb + kOff[t2][cc]);
                    s = MFMA32(kf, qb[cc], s);
                }
#pragma unroll
                for (int g = 0; g < 4; ++g) {
#pragma unroll
                    for (int r = 0; r < 4; ++r) {
                        float p = __builtin_amdgcn_exp2f(s[4 * g + r]);
                        l_r += p;
                        preg[t2][g][r] = (half_t)p;
                    }
                }
            }

            // P redistribution via permlane32_swap (replaces Pm LDS trip).
            // pf[cc] needs kv = cc*16 + 8*hl + j, q = ql. Own regs hold
            // kv = t2*32 + 8g + 4*hl + r. With A = preg[cc>>1][(cc&1)*2]
            // (g even), B = preg[cc>>1][(cc&1)*2+1] (g odd):
            //   swap(A_d, B_d) -> r[0] = [A.row0 | B.row0] = pf word d
            //                     r[1] = [A.row1 | B.row1] = pf word d+2
            half8 pf[4];
#pragma unroll
            for (int cc = 0; cc < 4; ++cc) {
                half4v pA = preg[cc >> 1][(cc & 1) * 2];
                half4v pB = preg[cc >> 1][(cc & 1) * 2 + 1];
                unsigned ad[2], bd[2];
                __builtin_memcpy(ad, &pA, 8);
                __builtin_memcpy(bd, &pB, 8);
                auto r0 = __builtin_amdgcn_permlane32_swap(ad[0], bd[0], false, false);
                auto r1 = __builtin_amdgcn_permlane32_swap(ad[1], bd[1], false, false);
                unsigned pfw[4] = {r0[0], r1[0], r0[1], r1[1]};
                __builtin_memcpy(&pf[cc], pfw, 16);
            }

            // O^T += V^T . P^T
#pragma unroll
            for (int dt = 0; dt < 2; ++dt)
#pragma unroll
                for (int cc = 0; cc < 4; ++cc) {
                    half8 vf = *(const half8*)(KVb + vOff[dt][cc]);
                    oacc[dt] = MFMA32(vf, pf[cc], oacc[dt]);
                }

            asm volatile("" ::: "memory");
            __builtin_amdgcn_s_barrier();          // readers of buf kk done
        }
    }

    // l: pair lanes (lane, lane^32) share the q column
    l_r += __shfl_xor(l_r, 32);
    const float inv = 1.0f / l_r;

    half_t* aorow = ao + ((size_t)(b * 1024 + i0w + ql)) * 1024 + h * 64;
#pragma unroll
    for (int dt = 0; dt < 2; ++dt)
#pragma unroll
        for (int g = 0; g < 4; ++g) {
            const int d0 = dt * 32 + 8 * g + 4 * hl;
            half4v oh;
#pragma unroll
            for (int r = 0; r < 4; ++r) oh[r] = (half_t)(oacc[dt][4 * g + r] * inv);
            *(half4v*)(aorow + d0) = oh;
        }
}

extern "C" void kernel_launch(void* const* d_in, const int* in_sizes, int n_in,
                              void* d_out, int out_size, void* d_ws, size_t ws_size,
                              hipStream_t stream) {
    const float* q     = (const float*)d_in[0];
    const float* w_in  = (const float*)d_in[1];
    const float* b_in  = (const float*)d_in[2];
    const float* w_out = (const float*)d_in[3];
    const float* b_out = (const float*)d_in[4];
    const float* pe    = (const float*)d_in[5];
    float* out = (float*)d_out;

    half_t* ws = (half_t*)d_ws;
    half_t* q16   = ws;
    half_t* w16   = q16 + 4194304;
    half_t* wo16  = w16 + 3145728;
    half_t* pe16  = wo16 + 1048576;      // 160x64 padded
    half_t* qh16  = pe16 + 10240;
    half_t* kh16  = qh16 + 4194304;
    half_t* vt16  = kh16 + 4194304;
    half_t* ao16  = vt16 + 4194304;

    cast_kernel<<<2048, 256, 0, stream>>>(q, w_in, w_out, pe, q16, w16, wo16, pe16);
    qkv_gemm<<<768, 256, 0, stream>>>(q16, w16, b_in, qh16, kh16, vt16);
    attn_mfma<<<512, 256, 0, stream>>>(qh16, kh16, vt16, pe16, ao16);
    out_gemm<<<512, 256, 0, stream>>>(ao16, wo16, b_out, out);
}

// Round 4
// 175.175 us; speedup vs baseline: 1.0330x; 1.0149x over previous
//
#include <hip/hip_runtime.h>
#include <math.h>

typedef _Float16 half_t;
typedef _Float16 half8 __attribute__((ext_vector_type(8)));
typedef _Float16 half4v __attribute__((ext_vector_type(4)));
typedef float float4v __attribute__((ext_vector_type(4)));
typedef float float16v __attribute__((ext_vector_type(16)));

#define AS1 __attribute__((address_space(1)))
#define AS3 __attribute__((address_space(3)))

#define MFMA16(a, b, c) __builtin_amdgcn_mfma_f32_16x16x32_f16((a), (b), (c), 0, 0, 0)
#define MFMA32(a, b, c) __builtin_amdgcn_mfma_f32_32x32x16_f16((a), (b), (c), 0, 0, 0)

// exp2-domain softmax: q is pre-scaled by 0.125*log2(e) in qkv_gemm.
#define QSCALE 0.18033688f          // 0.125 * 1.44269504
#define TABOFF 2.88539008f          // 2.0 * 1.44269504

__device__ __forceinline__ void gload16(const half_t* g, half_t* l) {
    __builtin_amdgcn_global_load_lds((const AS1 void*)g, (AS3 void*)l, 16, 0, 0);
}

__device__ __forceinline__ int iclamp(int v, int lo, int hi) {
    return v < lo ? lo : (v > hi ? hi : v);
}

__device__ __forceinline__ unsigned pkrtz_bits(float a, float b) {
    auto w = __builtin_amdgcn_cvt_pkrtz(a, b);   // __fp16 ext_vector(2)
    unsigned u;
    __builtin_memcpy(&u, &w, 4);
    return u;
}

// =====================================================================
// cast: fp32 -> fp16 for q, W_in, W_out, rel_pe (padded to 160 rows)
// =====================================================================
__global__ __launch_bounds__(256) void cast_kernel(
    const float* __restrict__ q, const float* __restrict__ w_in,
    const float* __restrict__ w_out, const float* __restrict__ pe,
    half_t* __restrict__ q16, half_t* __restrict__ w16,
    half_t* __restrict__ wo16, half_t* __restrict__ pe16)
{
    const int tid = blockIdx.x * 256 + threadIdx.x;
    const int stride = gridDim.x * 256;
    for (int i = tid; i < 1048576; i += stride) {
        float4 v = ((const float4*)q)[i];
        *(half4v*)(q16 + (size_t)i * 4) =
            (half4v){(half_t)v.x, (half_t)v.y, (half_t)v.z, (half_t)v.w};
    }
    for (int i = tid; i < 786432; i += stride) {
        float4 v = ((const float4*)w_in)[i];
        *(half4v*)(w16 + (size_t)i * 4) =
            (half4v){(half_t)v.x, (half_t)v.y, (half_t)v.z, (half_t)v.w};
    }
    for (int i = tid; i < 262144; i += stride) {
        float4 v = ((const float4*)w_out)[i];
        *(half4v*)(wo16 + (size_t)i * 4) =
            (half4v){(half_t)v.x, (half_t)v.y, (half_t)v.z, (half_t)v.w};
    }
    for (int i = tid; i < 2064; i += stride) {
        float4 v = ((const float4*)pe)[i];
        *(half4v*)(pe16 + (size_t)i * 4) =
            (half4v){(half_t)v.x, (half_t)v.y, (half_t)v.z, (half_t)v.w};
    }
    for (int i = tid; i < 496; i += stride) {   // pad rows 129..159 = 0
        *(half4v*)(pe16 + 8256 + (size_t)i * 4) = (half4v){0, 0, 0, 0};
    }
}

// =====================================================================
// fp16 MFMA NT GEMM, 128x128 tile, BK=32, 256 thr (4 waves in 2x2).
// 1-D grid, XCD-aware rectangle mapping. (R4 version — measured good.)
// =====================================================================
__global__ __launch_bounds__(256) void qkv_gemm(
    const half_t* __restrict__ A, const half_t* __restrict__ W,
    const float* __restrict__ bias,
    half_t* __restrict__ qh, half_t* __restrict__ kh, half_t* __restrict__ vt)
{
    __shared__ half_t As[128 * 32];
    __shared__ half_t Bs[128 * 32];
    const int K = 1024;
    const int tid = threadIdx.x, lane = tid & 63, wid = tid >> 6;
    const int wm = wid & 1, wn = wid >> 1;
    const int bid = blockIdx.x;
    const int xcd = bid & 7, idx = bid >> 3;
    const int m0 = (((xcd >> 1) << 3) + (idx & 7)) * 128;
    const int n0 = (((xcd & 1) * 12) + (idx >> 3)) * 128;

    const half_t* gA[2]; const half_t* gB[2];
    half_t* lA[2]; half_t* lB[2];
    {
        const int base = wid * 128;
#pragma unroll
        for (int c = 0; c < 2; ++c) {
            int slot = base + c * 64 + lane;
            int row = slot >> 2;
            int ch = (slot & 3) ^ ((row >> 1) & 3);
            gA[c] = A + (size_t)(m0 + row) * K + ch * 8;
            gB[c] = W + (size_t)(n0 + row) * K + ch * 8;
            lA[c] = As + (base + c * 64) * 8;
            lB[c] = Bs + (base + c * 64) * 8;
        }
    }
    int aOff[4], bOff[4];
#pragma unroll
    for (int i = 0; i < 4; ++i) {
        int ra = wm * 64 + i * 16 + (lane & 15);
        aOff[i] = ra * 32 + (((lane >> 4) ^ ((ra >> 1) & 3)) * 8);
        int rb = wn * 64 + i * 16 + (lane & 15);
        bOff[i] = rb * 32 + (((lane >> 4) ^ ((rb >> 1) & 3)) * 8);
    }
    float4v acc[4][4];
#pragma unroll
    for (int i = 0; i < 4; ++i)
#pragma unroll
        for (int j = 0; j < 4; ++j) acc[i][j] = (float4v){0.f, 0.f, 0.f, 0.f};

    for (int k0 = 0; k0 < K; k0 += 32) {
        __syncthreads();
        gload16(gA[0], lA[0]); gload16(gA[1], lA[1]);
        gload16(gB[0], lB[0]); gload16(gB[1], lB[1]);
        gA[0] += 32; gA[1] += 32; gB[0] += 32; gB[1] += 32;
        __syncthreads();
        half8 af[4], bf[4];
#pragma unroll
        for (int i = 0; i < 4; ++i) af[i] = *(const half8*)(As + aOff[i]);
#pragma unroll
        for (int j = 0; j < 4; ++j) bf[j] = *(const half8*)(Bs + bOff[j]);
#pragma unroll
        for (int i = 0; i < 4; ++i)
#pragma unroll
            for (int j = 0; j < 4; ++j)
                acc[i][j] = MFMA16(af[i], bf[j], acc[i][j]);
    }

    const int part = n0 >> 10;
#pragma unroll
    for (int ni = 0; ni < 4; ++ni) {
        const int col = n0 + wn * 64 + ni * 16 + (lane & 15);
        const float bv = bias[col];
        const int hh = (col >> 6) & 15, d = col & 63;
#pragma unroll
        for (int mi = 0; mi < 4; ++mi) {
            const int r0 = m0 + wm * 64 + mi * 16 + ((lane >> 4) << 2);
            const int bb = r0 >> 10, l0 = r0 & 1023;
            if (part == 0) {
#pragma unroll
                for (int r = 0; r < 4; ++r)
                    qh[(((size_t)(bb * 16 + hh) * 1024) + l0 + r) * 64 + d] =
                        (half_t)((acc[mi][ni][r] + bv) * QSCALE);
            } else if (part == 1) {
#pragma unroll
                for (int r = 0; r < 4; ++r)
                    kh[(((size_t)(bb * 16 + hh) * 1024) + l0 + r) * 64 + d] =
                        (half_t)(acc[mi][ni][r] + bv);
            } else {
                half4v pk;
#pragma unroll
                for (int r = 0; r < 4; ++r) pk[r] = (half_t)(acc[mi][ni][r] + bv);
                *(half4v*)(vt + ((size_t)(bb * 16 + hh) * 64 + d) * 1024 + l0) = pk;
            }
        }
    }
}

// =====================================================================
// out GEMM: 128x64 tiles -> 512 blocks (2/CU). (R9 version — banked win.)
// =====================================================================
__global__ __launch_bounds__(256) void out_gemm(
    const half_t* __restrict__ A, const half_t* __restrict__ W,
    const float* __restrict__ bias, float* __restrict__ C)
{
    __shared__ half_t As[128 * 32];
    __shared__ half_t Bs[64 * 32];
    const int K = 1024;
    const int tid = threadIdx.x, lane = tid & 63, wid = tid >> 6;
    const int wm = wid & 1, wn = wid >> 1;
    const int bid = blockIdx.x;
    const int xcd = bid & 7, idx = bid >> 3;
    const int m0 = ((xcd << 2) + (idx >> 4)) * 128;
    const int n0 = (idx & 15) * 64;

    const half_t* gA[2]; const half_t* gB1;
    half_t* lA[2]; half_t* lB1;
    {
        const int base = wid * 128;
#pragma unroll
        for (int c = 0; c < 2; ++c) {
            int slot = base + c * 64 + lane;
            int row = slot >> 2;
            int ch = (slot & 3) ^ ((row >> 1) & 3);
            gA[c] = A + (size_t)(m0 + row) * K + ch * 8;
            lA[c] = As + (base + c * 64) * 8;
        }
        int slotB = wid * 64 + lane;
        int rowB = slotB >> 2;
        int chB = (slotB & 3) ^ ((rowB >> 1) & 3);
        gB1 = W + (size_t)(n0 + rowB) * K + chB * 8;
        lB1 = Bs + (wid * 64) * 8;
    }
    int aOff[4], bOff[2];
#pragma unroll
    for (int i = 0; i < 4; ++i) {
        int ra = wm * 64 + i * 16 + (lane & 15);
        aOff[i] = ra * 32 + (((lane >> 4) ^ ((ra >> 1) & 3)) * 8);
    }
#pragma unroll
    for (int j = 0; j < 2; ++j) {
        int rb = wn * 32 + j * 16 + (lane & 15);
        bOff[j] = rb * 32 + (((lane >> 4) ^ ((rb >> 1) & 3)) * 8);
    }
    float4v acc[4][2];
#pragma unroll
    for (int i = 0; i < 4; ++i)
#pragma unroll
        for (int j = 0; j < 2; ++j) acc[i][j] = (float4v){0.f, 0.f, 0.f, 0.f};

    for (int k0 = 0; k0 < K; k0 += 32) {
        __syncthreads();
        gload16(gA[0], lA[0]); gload16(gA[1], lA[1]);
        gload16(gB1, lB1);
        gA[0] += 32; gA[1] += 32; gB1 += 32;
        __syncthreads();
        half8 af[4], bf[2];
#pragma unroll
        for (int i = 0; i < 4; ++i) af[i] = *(const half8*)(As + aOff[i]);
#pragma unroll
        for (int j = 0; j < 2; ++j) bf[j] = *(const half8*)(Bs + bOff[j]);
#pragma unroll
        for (int i = 0; i < 4; ++i)
#pragma unroll
            for (int j = 0; j < 2; ++j)
                acc[i][j] = MFMA16(af[i], bf[j], acc[i][j]);
    }

#pragma unroll
    for (int ni = 0; ni < 2; ++ni) {
        const int col = n0 + wn * 32 + ni * 16 + (lane & 15);
        const float bv = bias[col];
#pragma unroll
        for (int mi = 0; mi < 4; ++mi) {
            const int r0 = m0 + wm * 64 + mi * 16 + ((lane >> 4) << 2);
#pragma unroll
            for (int r = 0; r < 4; ++r)
                C[(size_t)(r0 + r) * 1024 + col] = acc[mi][ni][r] + bv;
        }
    }
}

// =====================================================================
// MFMA flash attention v6 (R4 = R3 + pkrtz type fix):
// far-tile constant bias. rel_pe[clip(j-i,-64,64)] is non-constant only
// in a 129-wide band; for a wave's 32 q-rows, only KV tiles overlapping
// [i0w-64, i0w+95] need the R2 gather (2-3 of 16). Far tiles: bias
// depends only on the C-column (q = ql), so the MFMA C-init is a
// loop-invariant float16v (s_lo_init / s_hi_init), selected by a
// wave-uniform scalar branch. Also: cvt_pkrtz packs P f32->f16
// (32->16 instrs), l accumulated as float4v (no serial dep chain).
// C/D layout: col=lane&31 (q), row=(reg&3)+8*(reg>>2)+4*(lane>>5) (kv).
// =====================================================================
__global__ __launch_bounds__(256) void attn_mfma(
    const half_t* __restrict__ qh, const half_t* __restrict__ kh,
    const half_t* __restrict__ vt, const half_t* __restrict__ pe,
    half_t* __restrict__ ao)
{
    __shared__ half_t KV[2 * 8192];        // dbuf [K 64x64 | V^T 64x64] swizzled
    __shared__ half_t R2[4 * 32 * 172];    // per-wave skewed bias, stride 172

    const int tid = threadIdx.x, lane = tid & 63, wid = tid >> 6;
    const int hl = lane >> 5, ql = lane & 31;
    const int bid = blockIdx.x;
    const int xcd = bid & 7, idx = bid >> 3;
    const int bh = xcd + ((idx >> 3) << 3);
    const int q0 = (idx & 7) * 128;
    const int h = bh & 15, b = bh >> 4;
    const int i0w = q0 + wid * 32;
    const int i0w_s = __builtin_amdgcn_readfirstlane(i0w);  // wave-uniform scalar
    const size_t hbase = (size_t)(b * 16 + h) * 64 * 1024;
    const half_t* Qg = qh + hbase;
    const half_t* Kg = kh + hbase;
    const half_t* Vg = vt + hbase;

    // ---- staging pointers (slots 0..511 K, 512..1023 V^T) ----
    const half_t* gS[4]; int lOff[4]; int ginc[4];
#pragma unroll
    for (int c = 0; c < 4; ++c) {
        const int slot0 = wid * 256 + c * 64;
        const int slot = slot0 + lane;
        if (slot0 < 512) {
            int srow = slot >> 3, sch = (slot & 7) ^ (srow & 7);
            gS[c] = Kg + srow * 64 + sch * 8;
            ginc[c] = 64 * 64;
            lOff[c] = slot0 * 8;
        } else {
            int s2 = slot - 512;
            int srow = s2 >> 3, sch = (s2 & 7) ^ (srow & 7);
            gS[c] = Vg + srow * 1024 + sch * 8;
            ginc[c] = 64;
            lOff[c] = 4096 + (slot0 - 512) * 8;
        }
    }

    // stage tile 0 into buffer 0 (DMA overlaps the R2 table build below)
#pragma unroll
    for (int c = 0; c < 4; ++c) { gload16(gS[c], KV + lOff[c]); gS[c] += ginc[c]; }

    // Q fragment: element [q=ql][d = cc*16 + hl*8 + j]
    const int qrow = i0w + ql;
    half8 qb[4];
#pragma unroll
    for (int cc = 0; cc < 4; ++cc)
        qb[cc] = *(const half8*)(Qg + (size_t)qrow * 64 + cc * 16 + hl * 8);

    // ---- build skewed bias table (wave-private): entry[il][ts] ----
    // interior ts = col+4+il (col = rel+64); plateaus: [0, il+4] = col0,
    // [il+132, il+139] = col128. Read clamp hi = 128+((ql+3)&~3).
    half_t* r2w = R2 + wid * (32 * 172);
#pragma unroll
    for (int j2 = 0; j2 < 5; ++j2) {
        float16v c;
#pragma unroll
        for (int r = 0; r < 16; ++r) c[r] = 0.f;
#pragma unroll
        for (int cc = 0; cc < 4; ++cc) {
            half8 pb = *(const half8*)(pe + (size_t)(j2 * 32 + ql) * 64 + cc * 16 + hl * 8);
            c = MFMA32(qb[cc], pb, c);
        }
        const int col = j2 * 32 + ql;
        if (col < 129) {
#pragma unroll
            for (int reg = 0; reg < 16; ++reg) {
                const int il = (reg & 3) + 8 * (reg >> 2) + 4 * hl;
                const half_t hv = (half_t)(c[reg] - TABOFF);
                if (col == 0) {
                    for (int ts = 0; ts <= il + 4; ++ts) r2w[il * 172 + ts] = hv;
                } else if (col == 128) {
                    for (int ts = il + 132; ts <= il + 139; ++ts) r2w[il * 172 + ts] = hv;
                } else {
                    r2w[il * 172 + col + 4 + il] = hv;
                }
            }
        }
    }
    // table committed before reads (wave-private LDS)
    asm volatile("s_waitcnt lgkmcnt(0)" ::: "memory");

    const half_t* r2row = r2w + ql * 172;

    // far-tile constant C-inits: bias depends only on q-col (=ql) there.
    // lo plateau value at ts=0, hi plateau at ts=ql+132 (row ql).
    const float c_lo = (float)r2row[0];
    const float c_hi = (float)r2row[ql + 132];
    float16v s_lo_init, s_hi_init;
#pragma unroll
    for (int r = 0; r < 16; ++r) { s_lo_init[r] = c_lo; s_hi_init[r] = c_hi; }

    // ---- frag LDS offsets (within one 8192-half buffer) ----
    int kOff[2][4], vOff[2][4];
#pragma unroll
    for (int t2 = 0; t2 < 2; ++t2)
#pragma unroll
        for (int cc = 0; cc < 4; ++cc) {
            int row = t2 * 32 + ql;
            int ch = (cc * 2 + hl) ^ (row & 7);
            kOff[t2][cc] = row * 64 + ch * 8;
            vOff[t2][cc] = 4096 + row * 64 + ch * 8;
        }

    const int hiC = 128 + ((ql + 3) & ~3);   // per-thread bias clamp (mult of 4)

    float4v lacc = (float4v){0.f, 0.f, 0.f, 0.f};
    float16v oacc[2];
#pragma unroll
    for (int dt = 0; dt < 2; ++dt)
#pragma unroll
        for (int r = 0; r < 16; ++r) oacc[dt][r] = 0.f;

    for (int kt2 = 0; kt2 < 8; ++kt2) {
#pragma unroll
        for (int kk = 0; kk < 2; ++kk) {
            const int kt = kt2 * 2 + kk;
            // prefetch tile kt+1 into the other buffer; keep it in flight
            if (kt < 15) {
#pragma unroll
                for (int c = 0; c < 4; ++c) {
                    gload16(gS[c], KV + (kk ^ 1) * 8192 + lOff[c]);
                    gS[c] += ginc[c];
                }
                asm volatile("s_waitcnt vmcnt(4)" ::: "memory"); // own tile-kt loads done
            } else {
                asm volatile("s_waitcnt vmcnt(0)" ::: "memory");
            }
            __builtin_amdgcn_s_barrier();          // all waves' tile-kt DMA landed
            asm volatile("" ::: "memory");

            const half_t* KVb = KV + kk * 8192;
            const int kt64 = kt << 6;
            const bool far_hi = (kt64 >= i0w_s + 95);    // all rel >= 64
            const bool far_lo = (kt64 <= i0w_s - 127);   // all rel <= -64

            // S^T = K.Q^T with bias C-init; p = exp2(s) kept in registers
            unsigned pw[2][4][2];   // packed f16 P words [t2][g][r-pair]
#pragma unroll
            for (int t2 = 0; t2 < 2; ++t2) {
                float16v s;
                if (far_hi) {
                    s = s_hi_init;
                } else if (far_lo) {
                    s = s_lo_init;
                } else {
#pragma unroll
                    for (int g = 0; g < 4; ++g) {
                        int traw = kt64 + t2 * 32 + 8 * g + 4 * hl + 64 - i0w;
                        int tsb = iclamp(traw, -4, hiC) + 4;
                        half4v bh4 = *(const half4v*)(r2row + tsb);
#pragma unroll
                        for (int r = 0; r < 4; ++r) s[4 * g + r] = (float)bh4[r];
                    }
                }
#pragma unroll
                for (int cc = 0; cc < 4; ++cc) {
                    half8 kf = *(const half8*)(KVb + kOff[t2][cc]);
                    s = MFMA32(kf, qb[cc], s);
                }
#pragma unroll
                for (int g = 0; g < 4; ++g) {
                    float p0 = __builtin_amdgcn_exp2f(s[4 * g + 0]);
                    float p1 = __builtin_amdgcn_exp2f(s[4 * g + 1]);
                    float p2 = __builtin_amdgcn_exp2f(s[4 * g + 2]);
                    float p3 = __builtin_amdgcn_exp2f(s[4 * g + 3]);
                    lacc += (float4v){p0, p1, p2, p3};
                    pw[t2][g][0] = pkrtz_bits(p0, p1);
                    pw[t2][g][1] = pkrtz_bits(p2, p3);
                }
            }

            // P redistribution via permlane32_swap (T12). pf[cc] word d:
            //   swap(A_d, B_d) -> r[0] = [A.row0 | B.row0] = word d
            //                     r[1] = [A.row1 | B.row1] = word d+2
            // A = pw[cc>>1][(cc&1)*2] (even g), B = odd g.
            half8 pf[4];
#pragma unroll
            for (int cc = 0; cc < 4; ++cc) {
                const int t2c = cc >> 1, ge = (cc & 1) * 2;
                auto r0 = __builtin_amdgcn_permlane32_swap(
                    pw[t2c][ge][0], pw[t2c][ge + 1][0], false, false);
                auto r1 = __builtin_amdgcn_permlane32_swap(
                    pw[t2c][ge][1], pw[t2c][ge + 1][1], false, false);
                unsigned pfw[4] = {r0[0], r1[0], r0[1], r1[1]};
                __builtin_memcpy(&pf[cc], pfw, 16);
            }

            // O^T += V^T . P^T
#pragma unroll
            for (int dt = 0; dt < 2; ++dt)
#pragma unroll
                for (int cc = 0; cc < 4; ++cc) {
                    half8 vf = *(const half8*)(KVb + vOff[dt][cc]);
                    oacc[dt] = MFMA32(vf, pf[cc], oacc[dt]);
                }

            asm volatile("" ::: "memory");
            __builtin_amdgcn_s_barrier();          // readers of buf kk done
        }
    }

    // l: reduce float4 partials, then pair lanes (lane, lane^32)
    float l_r = lacc[0] + lacc[1] + lacc[2] + lacc[3];
    l_r += __shfl_xor(l_r, 32);
    const float inv = 1.0f / l_r;

    half_t* aorow = ao + ((size_t)(b * 1024 + i0w + ql)) * 1024 + h * 64;
#pragma unroll
    for (int dt = 0; dt < 2; ++dt)
#pragma unroll
        for (int g = 0; g < 4; ++g) {
            const int d0 = dt * 32 + 8 * g + 4 * hl;
            half4v oh;
#pragma unroll
            for (int r = 0; r < 4; ++r) oh[r] = (half_t)(oacc[dt][4 * g + r] * inv);
            *(half4v*)(aorow + d0) = oh;
        }
}

extern "C" void kernel_launch(void* const* d_in, const int* in_sizes, int n_in,
                              void* d_out, int out_size, void* d_ws, size_t ws_size,
                              hipStream_t stream) {
    const float* q     = (const float*)d_in[0];
    const float* w_in  = (const float*)d_in[1];
    const float* b_in  = (const float*)d_in[2];
    const float* w_out = (const float*)d_in[3];
    const float* b_out = (const float*)d_in[4];
    const float* pe    = (const float*)d_in[5];
    float* out = (float*)d_out;

    half_t* ws = (half_t*)d_ws;
    half_t* q16   = ws;
    half_t* w16   = q16 + 4194304;
    half_t* wo16  = w16 + 3145728;
    half_t* pe16  = wo16 + 1048576;      // 160x64 padded
    half_t* qh16  = pe16 + 10240;
    half_t* kh16  = qh16 + 4194304;
    half_t* vt16  = kh16 + 4194304;
    half_t* ao16  = vt16 + 4194304;

    cast_kernel<<<2048, 256, 0, stream>>>(q, w_in, w_out, pe, q16, w16, wo16, pe16);
    qkv_gemm<<<768, 256, 0, stream>>>(q16, w16, b_in, qh16, kh16, vt16);
    attn_mfma<<<512, 256, 0, stream>>>(qh16, kh16, vt16, pe16, ao16);
    out_gemm<<<512, 256, 0, stream>>>(ao16, wo16, b_out, out);
}